// Round 1
// baseline (507.742 us; speedup 1.0000x reference)
//
#include <hip/hip_runtime.h>
#include <math.h>

#define CC 256   // columns
#define NN 512   // neurons per column
#define DD 256   // input dim (= D_CTX)
#define BB 64    // batch
#define KK 24    // top-k
#define WCAP 48  // winner-list capacity per row (>=24, slack for fp ties)

#define SMEM_FLOATS (BB * NN + BB + BB + BB + BB * WCAP + BB * WCAP)
#define SMEM_BYTES (SMEM_FLOATS * 4)

// Pre-transpose x (and fold FEEDBACK=0.3 into the context input) so the main
// kernel can read x values as wave-uniform scalar loads: xT[d][b].
__global__ void transpose_x_kernel(const float* __restrict__ x_in,
                                   const float* __restrict__ x_ctx,
                                   float* __restrict__ xT_in,
                                   float* __restrict__ xT_ctx) {
  int idx = blockIdx.x * blockDim.x + threadIdx.x;  // 0 .. BB*DD-1
  int d = idx >> 6;   // /64
  int b = idx & 63;
  xT_in[idx] = x_in[b * DD + d];
  xT_ctx[idx] = 0.3f * x_ctx[b * DD + d];
}

__launch_bounds__(512, 1)
__global__ void cortical_main(const float* __restrict__ x_in,     // [B][D] (for errors)
                              const float* __restrict__ xT_in,    // [D][B]
                              const float* __restrict__ xT_ctx,   // [D][B], pre-scaled by 0.3
                              const float* __restrict__ W_ff,     // [C][D][N]
                              const float* __restrict__ W_ctx,    // [C][D][N]
                              const float* __restrict__ W_pred,   // [C][N][D]
                              const float* __restrict__ bias,     // [C][N]
                              const float* __restrict__ avg_act,  // [C][N]
                              float* __restrict__ out_act,        // [B][C][N]
                              float* __restrict__ out_pred,       // [B][C][D]
                              float* __restrict__ out_err) {      // [B][C][D]
  extern __shared__ float smem[];
  float* mat = smem;                      // [BB][NN] transposed drive / raw act
  float* thr = smem + BB * NN;            // [BB] kth-largest boosted value
  float* scl = thr + BB;                  // [BB] K / (sum + 1e-8)
  int* wcnt = (int*)(scl + BB);           // [BB] winner counts
  int* wn = wcnt + BB;                    // [BB][WCAP] winner neuron idx
  float* wvv = (float*)(wn + BB * WCAP);  // [BB][WCAP] winner act value

  const int c = blockIdx.x;
  const int t = threadIdx.x;  // neuron index n = t
  const int lane = t & 63;

  if (t < BB) wcnt[t] = 0;

  // ---------------- Phase A: drive = x@Wff + 0.3*xctx@Wctx + bias ----------
  float acc[BB];
#pragma unroll
  for (int b = 0; b < BB; ++b) acc[b] = 0.f;

  const float* pff = W_ff + (size_t)c * DD * NN + t;
  const float* pcx = W_ctx + (size_t)c * DD * NN + t;

#pragma unroll 2
  for (int d = 0; d < DD; ++d) {
    float a = pff[(size_t)d * NN];  // coalesced across lanes
    float e = pcx[(size_t)d * NN];
    const float* xf = xT_in + d * BB;   // uniform addresses -> s_load
    const float* xc = xT_ctx + d * BB;  // uniform addresses -> s_load
#pragma unroll
    for (int b = 0; b < BB; ++b) acc[b] = fmaf(xf[b], a, acc[b]);
#pragma unroll
    for (int b = 0; b < BB; ++b) acc[b] = fmaf(xc[b], e, acc[b]);
  }

  const float biasv = bias[c * NN + t];
  const float boost = log1pf(0.05f / (avg_act[c * NN + t] + 1e-6f));
#pragma unroll
  for (int b = 0; b < BB; ++b) acc[b] += biasv;  // acc = drive

  __syncthreads();  // wcnt init visible; mat safe to write
#pragma unroll
  for (int b = 0; b < BB; ++b) mat[b * NN + t] = acc[b] + boost;  // boosted
  __syncthreads();

  // ---------------- Phase B1: exact kth-largest per row (wave-local) -------
  {
    const int w = t >> 6;  // wave id 0..7, rows 8w..8w+7
    for (int r = w * 8; r < w * 8 + 8; ++r) {
      float v[8];
#pragma unroll
      for (int j = 0; j < 8; ++j) v[j] = mat[r * NN + lane + 64 * j];
      float kth = 0.f;
      for (int it = 0; it < KK; ++it) {
        float m = v[0];
#pragma unroll
        for (int j = 1; j < 8; ++j) m = fmaxf(m, v[j]);
#pragma unroll
        for (int off = 1; off <= 32; off <<= 1) m = fmaxf(m, __shfl_xor(m, off));
        kth = m;
        // remove exactly one instance of m (lowest lane, lowest slot)
        bool mine = false;
#pragma unroll
        for (int j = 0; j < 8; ++j) mine = mine || (v[j] == m);
        unsigned long long msk = __ballot(mine);
        int first = __ffsll(msk) - 1;
        if (lane == first) {
          bool done = false;
#pragma unroll
          for (int j = 0; j < 8; ++j) {
            bool cnd = (!done) && (v[j] == m);
            if (cnd) v[j] = -INFINITY;
            done = done || cnd;
          }
        }
      }
      if (lane == 0) thr[r] = kth;
    }
  }
  __syncthreads();

  // ---------------- Phase B2: raw = relu(drive) * (boosted >= thr) ---------
#pragma unroll
  for (int b = 0; b < BB; ++b) {
    float tb = thr[b];
    float raw = ((acc[b] + boost) >= tb) ? fmaxf(acc[b], 0.f) : 0.f;
    mat[b * NN + t] = raw;
  }
  __syncthreads();

  // ---------------- Phase B3: row sums -> normalization scale --------------
  {
    const int w = t >> 6;
    for (int r = w * 8; r < w * 8 + 8; ++r) {
      float s = 0.f;
#pragma unroll
      for (int j = 0; j < 8; ++j) s += mat[r * NN + lane + 64 * j];
#pragma unroll
      for (int off = 1; off <= 32; off <<= 1) s += __shfl_xor(s, off);
      if (lane == 0) scl[r] = (float)KK / (s + 1e-8f);
    }
  }
  __syncthreads();

  // ---------------- Phase B4: write activations + build winner lists -------
  for (int b = 0; b < BB; ++b) {
    float raw = mat[b * NN + t];  // LDS re-read avoids runtime-indexed acc[]
    float act = raw * scl[b];
    out_act[(size_t)b * (CC * NN) + c * NN + t] = act;
    if (act > 0.f) {
      int idx = atomicAdd(&wcnt[b], 1);
      if (idx < WCAP) {
        wn[b * WCAP + idx] = t;
        wvv[b * WCAP + idx] = act;
      }
    }
  }
  __syncthreads();

  // ---------------- Phase C: sparse predictions + errors -------------------
  {
    const int d = t & (DD - 1);
    const int g = t >> 8;  // 0 or 1 -> batch halves
    const float* wp = W_pred + (size_t)c * NN * DD + d;
    for (int bb = g * 32; bb < g * 32 + 32; ++bb) {
      int cnt = wcnt[bb];
      if (cnt > WCAP) cnt = WCAP;
      float p0 = 0.f, p1 = 0.f, p2 = 0.f, p3 = 0.f;
      int i = 0;
      for (; i + 4 <= cnt; i += 4) {
        int n0 = wn[bb * WCAP + i + 0];
        int n1 = wn[bb * WCAP + i + 1];
        int n2 = wn[bb * WCAP + i + 2];
        int n3 = wn[bb * WCAP + i + 3];
        float a0 = wvv[bb * WCAP + i + 0];
        float a1 = wvv[bb * WCAP + i + 1];
        float a2 = wvv[bb * WCAP + i + 2];
        float a3 = wvv[bb * WCAP + i + 3];
        p0 = fmaf(a0, wp[(size_t)n0 * DD], p0);
        p1 = fmaf(a1, wp[(size_t)n1 * DD], p1);
        p2 = fmaf(a2, wp[(size_t)n2 * DD], p2);
        p3 = fmaf(a3, wp[(size_t)n3 * DD], p3);
      }
      for (; i < cnt; ++i) {
        p0 = fmaf(wvv[bb * WCAP + i], wp[(size_t)wn[bb * WCAP + i] * DD], p0);
      }
      float p = (p0 + p1) + (p2 + p3);
      out_pred[(size_t)bb * (CC * DD) + c * DD + d] = p;
      out_err[(size_t)bb * (CC * DD) + c * DD + d] = x_in[bb * DD + d] - p;
    }
  }
}

extern "C" void kernel_launch(void* const* d_in, const int* in_sizes, int n_in,
                              void* d_out, int out_size, void* d_ws, size_t ws_size,
                              hipStream_t stream) {
  const float* x_in = (const float*)d_in[0];
  const float* x_ctx = (const float*)d_in[1];
  const float* W_ff = (const float*)d_in[2];
  const float* W_ctx = (const float*)d_in[3];
  const float* W_pred = (const float*)d_in[4];
  const float* bias = (const float*)d_in[5];
  const float* avg = (const float*)d_in[6];

  float* out = (float*)d_out;
  float* out_act = out;                                // [B][C][N]
  float* out_pred = out + (size_t)BB * CC * NN;        // [B][C][D]
  float* out_err = out_pred + (size_t)BB * CC * DD;    // [B][C][D]

  float* xT_in = (float*)d_ws;         // [D][B]
  float* xT_ctx = xT_in + BB * DD;     // [D][B]

  hipFuncSetAttribute((const void*)cortical_main,
                      hipFuncAttributeMaxDynamicSharedMemorySize, SMEM_BYTES);

  transpose_x_kernel<<<(BB * DD) / 256, 256, 0, stream>>>(x_in, x_ctx, xT_in, xT_ctx);
  cortical_main<<<CC, 512, SMEM_BYTES, stream>>>(x_in, xT_in, xT_ctx, W_ff, W_ctx,
                                                 W_pred, bias, avg, out_act,
                                                 out_pred, out_err);
}

// Round 2
// 218.939 us; speedup vs baseline: 2.3191x; 2.3191x over previous
//
#include <hip/hip_runtime.h>
#include <math.h>

#define CC 256   // columns
#define NN 512   // neurons per column
#define DD 256   // input dim (= D_CTX)
#define BB 64    // batch
#define KK 24    // top-k
#define WCAP 48  // winner-list capacity per row (>=24, slack for fp ties)

// LDS layout (floats): mat[BB*NN] | thr[BB] | scl[BB] | boostS[NN] | wcnt[BB] | wlist[BB*WCAP*2]
#define MAT_F (BB * NN)
#define SMEM_FLOATS (MAT_F + BB + BB + NN + BB + BB * WCAP * 2)
#define SMEM_BYTES (SMEM_FLOATS * 4)

// Build xT[512][64]: d<256 -> x_in^T, d>=256 -> 0.3*x_ctx^T (FEEDBACK folded).
__global__ void transpose_x_kernel(const float* __restrict__ x_in,
                                   const float* __restrict__ x_ctx,
                                   float* __restrict__ xT) {
  int idx = blockIdx.x * blockDim.x + threadIdx.x;  // 0 .. 2*BB*DD-1
  int d = idx >> 6;
  int b = idx & 63;
  float v = (d < DD) ? x_in[b * DD + d] : 0.3f * x_ctx[b * DD + (d - DD)];
  xT[idx] = v;
}

__launch_bounds__(1024)
__global__ void cortical_main(const float* __restrict__ x_in,   // [B][D]
                              const float* __restrict__ xT,     // [2D][B] combined
                              const float* __restrict__ W_ff,   // [C][D][N]
                              const float* __restrict__ W_ctx,  // [C][D][N]
                              const float* __restrict__ W_pred, // [C][N][D]
                              const float* __restrict__ bias,   // [C][N]
                              const float* __restrict__ avg_act,// [C][N]
                              float* __restrict__ out_act,      // [B][C][N]
                              float* __restrict__ out_pred,     // [B][C][D]
                              float* __restrict__ out_err) {    // [B][C][D]
  extern __shared__ float smem[];
  float* mat = smem;                     // [BB][NN] boosted drive
  float* thr = smem + MAT_F;             // [BB]
  float* scl = thr + BB;                 // [BB] (unused slots kept for layout clarity)
  float* boostS = scl + BB;              // [NN]
  int* wcnt = (int*)(boostS + NN);       // [BB]
  float* wlist = (float*)(wcnt + BB);    // [BB][WCAP][2] = {val, idx-bits}

  const int c = blockIdx.x;
  const int t = threadIdx.x;
  const int lane = t & 63;
  const int wv = t >> 6;  // wave 0..15

  if (t < NN) boostS[t] = log1pf(0.05f / (avg_act[c * NN + t] + 1e-6f));
  __syncthreads();

  // ---------------- Phase A: drive GEMM, microtile 16b x 2n ----------------
  const int ng = t & 255;                      // n-group
  const int n0 = ng * 2;                       // 2 consecutive neurons
  const int b0 = __builtin_amdgcn_readfirstlane((t >> 8) * 16);  // 16 batches

  float acc[16][2];
#pragma unroll
  for (int i = 0; i < 16; ++i) { acc[i][0] = 0.f; acc[i][1] = 0.f; }

  const float* __restrict__ wf = W_ff + (size_t)c * DD * NN + n0;
  const float* __restrict__ wc = W_ctx + (size_t)c * DD * NN + n0;

#pragma unroll 4
  for (int d = 0; d < DD; ++d) {
    const float2 w = *reinterpret_cast<const float2*>(wf + (size_t)d * NN);
    const float* __restrict__ xp = xT + d * BB + b0;  // wave-uniform -> s_load
#pragma unroll
    for (int i = 0; i < 16; ++i) {
      const float xv = xp[i];
      acc[i][0] = fmaf(xv, w.x, acc[i][0]);
      acc[i][1] = fmaf(xv, w.y, acc[i][1]);
    }
  }
#pragma unroll 4
  for (int d = 0; d < DD; ++d) {
    const float2 w = *reinterpret_cast<const float2*>(wc + (size_t)d * NN);
    const float* __restrict__ xp = xT + (DD + d) * BB + b0;  // pre-scaled ctx
#pragma unroll
    for (int i = 0; i < 16; ++i) {
      const float xv = xp[i];
      acc[i][0] = fmaf(xv, w.x, acc[i][0]);
      acc[i][1] = fmaf(xv, w.y, acc[i][1]);
    }
  }

  const float2 bz = *reinterpret_cast<const float2*>(bias + (size_t)c * NN + n0);
  const float2 bo = *reinterpret_cast<const float2*>(boostS + n0);
#pragma unroll
  for (int i = 0; i < 16; ++i) {
    float d0v = acc[i][0] + bz.x;
    float d1v = acc[i][1] + bz.y;
    float2 m2;
    m2.x = d0v + bo.x;
    m2.y = d1v + bo.y;
    *reinterpret_cast<float2*>(mat + (size_t)(b0 + i) * NN + n0) = m2;  // boosted
  }
  __syncthreads();

  // ---------------- Phase B1: exact kth-largest per row (4 rows/wave) ------
  for (int r = wv * 4; r < wv * 4 + 4; ++r) {
    float v[8];
#pragma unroll
    for (int j = 0; j < 8; ++j) v[j] = mat[r * NN + lane + 64 * j];
    float kth = 0.f;
    for (int it = 0; it < KK; ++it) {
      float m = v[0];
#pragma unroll
      for (int j = 1; j < 8; ++j) m = fmaxf(m, v[j]);
#pragma unroll
      for (int off = 1; off <= 32; off <<= 1) m = fmaxf(m, __shfl_xor(m, off));
      kth = m;
      bool mine = false;
#pragma unroll
      for (int j = 0; j < 8; ++j) mine = mine || (v[j] == m);
      unsigned long long msk = __ballot(mine);
      int first = __ffsll((unsigned long long)msk) - 1;
      if (lane == first) {
        bool done = false;
#pragma unroll
        for (int j = 0; j < 8; ++j) {
          bool cnd = (!done) && (v[j] == m);
          if (cnd) v[j] = -INFINITY;
          done = done || cnd;
        }
      }
    }
    if (lane == 0) thr[r] = kth;
  }
  __syncthreads();

  // ------- Phase B2-4 fused (row-parallel): raw, sum, act write, winners ---
  for (int r = wv * 4; r < wv * 4 + 4; ++r) {
    const float tb = thr[r];
    float raw[8];
    float s = 0.f;
#pragma unroll
    for (int j = 0; j < 8; ++j) {
      const int n = lane + 64 * j;
      const float bv = mat[r * NN + n];
      const float rw = (bv >= tb) ? fmaxf(bv - boostS[n], 0.f) : 0.f;
      raw[j] = rw;
      s += rw;
    }
#pragma unroll
    for (int off = 1; off <= 32; off <<= 1) s += __shfl_xor(s, off);
    const float sc = (float)KK / (s + 1e-8f);

    int base = 0;
#pragma unroll
    for (int j = 0; j < 8; ++j) {
      const int n = lane + 64 * j;
      const float a = raw[j] * sc;
      out_act[(size_t)r * (CC * NN) + (size_t)c * NN + n] = a;
      const bool win = a > 0.f;
      unsigned long long m = __ballot(win);
      int pos = base + __popcll(m & ((1ull << lane) - 1ull));
      if (win && pos < WCAP) {
        const int slot = (r * WCAP + pos) * 2;
        wlist[slot] = a;
        reinterpret_cast<int*>(wlist)[slot + 1] = n;
      }
      base += (int)__popcll(m);
    }
    if (lane == 0) wcnt[r] = (base < WCAP) ? base : WCAP;
  }
  __syncthreads();

  // ---------------- Phase C: sparse predictions + errors -------------------
  {
    const int dq = t & 63;
    const int d0 = dq * 4;
    const int grp = t >> 6;  // 0..15 -> 4 batches each
    const float* __restrict__ wp = W_pred + (size_t)c * NN * DD;
    for (int bi = 0; bi < 4; ++bi) {
      const int b = grp * 4 + bi;
      const int cnt = wcnt[b];
      float4 p = make_float4(0.f, 0.f, 0.f, 0.f);
      float4 q = make_float4(0.f, 0.f, 0.f, 0.f);
      int i = 0;
      for (; i + 2 <= cnt; i += 2) {
        const int s0 = (b * WCAP + i) * 2;
        const int s1 = s0 + 2;
        const float a0 = wlist[s0];
        const int nn0 = reinterpret_cast<const int*>(wlist)[s0 + 1];
        const float a1 = wlist[s1];
        const int nn1 = reinterpret_cast<const int*>(wlist)[s1 + 1];
        const float4 w0 = *reinterpret_cast<const float4*>(wp + (size_t)nn0 * DD + d0);
        const float4 w1 = *reinterpret_cast<const float4*>(wp + (size_t)nn1 * DD + d0);
        p.x = fmaf(a0, w0.x, p.x); p.y = fmaf(a0, w0.y, p.y);
        p.z = fmaf(a0, w0.z, p.z); p.w = fmaf(a0, w0.w, p.w);
        q.x = fmaf(a1, w1.x, q.x); q.y = fmaf(a1, w1.y, q.y);
        q.z = fmaf(a1, w1.z, q.z); q.w = fmaf(a1, w1.w, q.w);
      }
      if (i < cnt) {
        const int s0 = (b * WCAP + i) * 2;
        const float a0 = wlist[s0];
        const int nn0 = reinterpret_cast<const int*>(wlist)[s0 + 1];
        const float4 w0 = *reinterpret_cast<const float4*>(wp + (size_t)nn0 * DD + d0);
        p.x = fmaf(a0, w0.x, p.x); p.y = fmaf(a0, w0.y, p.y);
        p.z = fmaf(a0, w0.z, p.z); p.w = fmaf(a0, w0.w, p.w);
      }
      float4 r4;
      r4.x = p.x + q.x; r4.y = p.y + q.y; r4.z = p.z + q.z; r4.w = p.w + q.w;
      const float4 xi = *reinterpret_cast<const float4*>(x_in + (size_t)b * DD + d0);
      float4 e4;
      e4.x = xi.x - r4.x; e4.y = xi.y - r4.y; e4.z = xi.z - r4.z; e4.w = xi.w - r4.w;
      *reinterpret_cast<float4*>(out_pred + (size_t)b * (CC * DD) + (size_t)c * DD + d0) = r4;
      *reinterpret_cast<float4*>(out_err + (size_t)b * (CC * DD) + (size_t)c * DD + d0) = e4;
    }
  }
}

extern "C" void kernel_launch(void* const* d_in, const int* in_sizes, int n_in,
                              void* d_out, int out_size, void* d_ws, size_t ws_size,
                              hipStream_t stream) {
  const float* x_in = (const float*)d_in[0];
  const float* x_ctx = (const float*)d_in[1];
  const float* W_ff = (const float*)d_in[2];
  const float* W_ctx = (const float*)d_in[3];
  const float* W_pred = (const float*)d_in[4];
  const float* bias = (const float*)d_in[5];
  const float* avg = (const float*)d_in[6];

  float* out = (float*)d_out;
  float* out_act = out;                              // [B][C][N]
  float* out_pred = out + (size_t)BB * CC * NN;      // [B][C][D]
  float* out_err = out_pred + (size_t)BB * CC * DD;  // [B][C][D]

  float* xT = (float*)d_ws;  // [2*DD][BB]

  hipFuncSetAttribute((const void*)cortical_main,
                      hipFuncAttributeMaxDynamicSharedMemorySize, SMEM_BYTES);

  transpose_x_kernel<<<(2 * BB * DD) / 256, 256, 0, stream>>>(x_in, x_ctx, xT);
  cortical_main<<<CC, 1024, SMEM_BYTES, stream>>>(x_in, xT, W_ff, W_ctx, W_pred,
                                                  bias, avg, out_act, out_pred,
                                                  out_err);
}